// Round 12
// baseline (93.848 us; speedup 1.0000x reference)
//
#include <hip/hip_runtime.h>
#include <hip/hip_bf16.h>

// Problem constants
#define NF 40   // fields f
#define NI 40   // in_sub i
#define NN 40   // out_sub n
#define ED 64   // embed D, d
#define NB 256  // batch b

typedef __attribute__((ext_vector_type(8))) short   short8;
typedef __attribute__((ext_vector_type(8))) __bf16  bf16x8;
typedef __attribute__((ext_vector_type(4))) float   f32x4;

__device__ __forceinline__ unsigned short f2bf(float x) {
    union { float f; unsigned u; } v; v.f = x;
    unsigned r = v.u + 0x7FFFu + ((v.u >> 16) & 1u);   // RNE
    return (unsigned short)(r >> 16);
}

__device__ __forceinline__ bf16x8 ld_frag(const unsigned short* p) {
    return __builtin_bit_cast(bf16x8, *(const short8*)p);
}

__device__ __forceinline__ f32x4 mfma16(bf16x8 a, bf16x8 b, f32x4 c) {
    return __builtin_amdgcn_mfma_f32_16x16x32_bf16(a, b, c, 0, 0, 0);
}

// ==========================================================================
// FAST PATH (tier 2): prep6 converts EVERYTHING to bf16 MFMA-ready layouts
// (streaming-coalesced, cold-cache-friendly); main9 = main8's verified
// structure with raw-copy staging from the L2/L3-warm ws.
//   BiP[b][i(48)][d(64)] = Bi[b][i][d]        (i>=40 -> 0)
//   B0T[b][D(64)][f(64)] = B0[b][f][D]        (f>=40 -> 0)
//   whp[n][D(64)][d(64)] = W[n][D][d]*h[n][d]
//   alp[n][i(48)][f(64)] = alpha[f][i][n]     (pads -> 0)
// ==========================================================================
#define BIP_N (48 * 64)   // 3072
#define B0T_N (64 * 64)   // 4096
#define WHP_N (64 * 64)   // 4096
#define ALP_N (48 * 64)   // 3072

// Prep6: 336 blocks x 256 thr (all roles verified in R7/R5 runs):
//   x <  256        : b = x    : BiP (coalesced) + B0T (LDS fp32 transpose)
//   256 <= x < 296  : n = x-256: whp (coalesced) + zero alp[n] pads
//   296 <= x < 336  : f = x-296: alpha slice, coalesced read, scatter write
__global__ __launch_bounds__(256) void gif_prep6(
        const float* __restrict__ B0, const float* __restrict__ Bi,
        const float* __restrict__ W, const float* __restrict__ alpha,
        const float* __restrict__ h,
        unsigned short* __restrict__ BiP, unsigned short* __restrict__ B0T,
        unsigned short* __restrict__ whp, unsigned short* __restrict__ alp) {
    const int x = blockIdx.x;
    const int t = threadIdx.x;

    if (x < NB) {
        const int b = x;
        __shared__ float sB0[NF][ED + 1];
        for (int idx = t; idx < NF * ED; idx += 256) {
            int f = idx >> 6, D = idx & 63;
            sB0[f][D] = B0[b * NF * ED + idx];
        }
        __syncthreads();
        for (int idx = t; idx < 48 * 64; idx += 256) {
            int i = idx >> 6, d = idx & 63;
            BiP[b * BIP_N + idx] = (i < NI) ? f2bf(Bi[b * NI * ED + i * ED + d])
                                            : (unsigned short)0;
        }
        for (int idx = t; idx < 64 * 64; idx += 256) {
            int D = idx >> 6, f = idx & 63;
            B0T[b * B0T_N + idx] = (f < NF) ? f2bf(sB0[f][D]) : (unsigned short)0;
        }
    } else if (x < NB + NN) {
        const int n = x - NB;
        for (int idx = t; idx < 64 * 64; idx += 256) {       // whp coalesced
            int d = idx & 63;
            whp[n * WHP_N + idx] = f2bf(W[n * ED * ED + idx] * h[n * ED + d]);
        }
        for (int idx = t; idx < 8 * 64; idx += 256)          // rows i 40..47
            alp[n * ALP_N + (40 + (idx >> 6)) * 64 + (idx & 63)] = 0;
        for (int idx = t; idx < 40 * 24; idx += 256) {       // cols f 40..63
            int i = idx / 24, f = 40 + idx - i * 24;
            alp[n * ALP_N + i * 64 + f] = 0;
        }
    } else {
        const int f = x - NB - NN;
        for (int idx = t; idx < NI * NN; idx += 256) {       // coalesced read
            int i = idx / NN, n = idx - i * NN;
            alp[n * ALP_N + i * 64 + f] = f2bf(alpha[(f * NI + i) * NN + n]);
        }
    }
}

// Main9: grid (64, 10) x 256 thr (4 waves) — main8's verified structure.
// Wave w owns n = ng*4+w; its 14 param frags loaded ONCE into registers.
// b-loop (4 iters): staging is now a raw int4 copy of pre-converted bf16
// (896 chunks incl. pads — no f2bf, no transpose, no pad pass in main);
// prefetch of b+1's chunks issued before the 48-MFMA body.
#define PSM 72
#define NCH 896   // 16B chunks per b: 384 (BiP 6KB) + 512 (B0T 8KB)

__global__ __launch_bounds__(256, 2) void gif_main9(
        const unsigned short* __restrict__ BiP,
        const unsigned short* __restrict__ B0T,
        const unsigned short* __restrict__ whp,
        const unsigned short* __restrict__ alp,
        float* __restrict__ out) {
    const int bg = blockIdx.x;         // 0..63 : b in [bg*4, bg*4+4)
    const int ng = blockIdx.y;         // 0..9  : n in [ng*4, ng*4+4)
    const int t = threadIdx.x;
    const int lane = t & 63, w = t >> 6;
    const int quad = lane >> 4, l15 = lane & 15, fo = quad * 8;
    const int n = ng * 4 + w;

    __shared__ __align__(16) unsigned short sBi[48 * PSM];  // [i][d]  6912 B
    __shared__ __align__(16) unsigned short sBT[64 * PSM];  // [D][f]  9216 B

    // ---- 1. staging loads for first b (raw int4 copies, issued first) ----
    int4 creg[4];
    {
        const int4* bip = (const int4*)(BiP + (size_t)(bg * 4) * BIP_N);
        const int4* b0t = (const int4*)(B0T + (size_t)(bg * 4) * B0T_N);
#pragma unroll
        for (int k = 0; k < 4; ++k) {
            const int c = t + k * 256;
            if (c < NCH) creg[k] = (c < 384) ? bip[c] : b0t[c - 384];
        }
    }

    // ---- 2. this wave's n-params: 14 b128 gathers, ONCE ----
    bf16x8 alA[3][2], whB[4][2];
    {
        const unsigned short* ap = alp + n * ALP_N;
        const unsigned short* wp = whp + n * WHP_N;
#pragma unroll
        for (int m = 0; m < 3; ++m)
#pragma unroll
            for (int s = 0; s < 2; ++s)
                alA[m][s] = ld_frag(&ap[(m * 16 + l15) * 64 + s * 32 + fo]);
#pragma unroll
        for (int tt = 0; tt < 4; ++tt)
#pragma unroll
            for (int s = 0; s < 2; ++s)
                whB[tt][s] = ld_frag(&wp[(tt * 16 + l15) * 64 + s * 32 + fo]);
    }

    // ---- 3. write first b's staging (pads included in the copy) ----
#pragma unroll
    for (int k = 0; k < 4; ++k) {
        const int c = t + k * 256;
        if (c < NCH) {
            unsigned short* dst = (c < 384)
                ? &sBi[(c >> 3) * PSM + (c & 7) * 8]
                : &sBT[((c - 384) >> 3) * PSM + ((c - 384) & 7) * 8];
            *(int4*)dst = creg[k];
        }
    }
    __syncthreads();

    // ---- 4. b-loop ----
#pragma unroll
    for (int j = 0; j < 4; ++j) {
        const int b = bg * 4 + j;

        if (j < 3) {   // prefetch next b's chunks into registers
            const int4* bip = (const int4*)(BiP + (size_t)(b + 1) * BIP_N);
            const int4* b0t = (const int4*)(B0T + (size_t)(b + 1) * B0T_N);
#pragma unroll
            for (int k = 0; k < 4; ++k) {
                const int c = t + k * 256;
                if (c < NCH) creg[k] = (c < 384) ? bip[c] : b0t[c - 384];
            }
        }

        // per-b fragments from LDS + 48-MFMA body
        bf16x8 biA[3][2];
#pragma unroll
        for (int m = 0; m < 3; ++m)
#pragma unroll
            for (int s = 0; s < 2; ++s)
                biA[m][s] = ld_frag(&sBi[(m * 16 + l15) * PSM + s * 32 + fo]);

        float p[4];
#pragma unroll
        for (int tt = 0; tt < 4; ++tt) {
            bf16x8 bb0 = ld_frag(&sBT[(tt * 16 + l15) * PSM + fo]);
            bf16x8 bb1 = ld_frag(&sBT[(tt * 16 + l15) * PSM + 32 + fo]);
            float acc = 0.f;
#pragma unroll
            for (int m = 0; m < 3; ++m) {
                f32x4 z = {0.f, 0.f, 0.f, 0.f};
                f32x4 T = mfma16(biA[m][0], whB[tt][0], z);
                T = mfma16(biA[m][1], whB[tt][1], T);
                f32x4 G = mfma16(alA[m][0], bb0, z);
                G = mfma16(alA[m][1], bb1, G);
                acc += T[0] * G[0] + T[1] * G[1] + T[2] * G[2] + T[3] * G[3];
            }
            p[tt] = acc;
        }
#pragma unroll
        for (int tt = 0; tt < 4; ++tt) {
            p[tt] += __shfl_xor(p[tt], 16, 64);
            p[tt] += __shfl_xor(p[tt], 32, 64);
        }
        float v = (quad == 0) ? p[0] : (quad == 1) ? p[1] : (quad == 2) ? p[2] : p[3];
        out[((size_t)b * NN + n) * ED + lane] = v;

        if (j < 3) {   // restage for b+1 between two barriers
            __syncthreads();
#pragma unroll
            for (int k = 0; k < 4; ++k) {
                const int c = t + k * 256;
                if (c < NCH) {
                    unsigned short* dst = (c < 384)
                        ? &sBi[(c >> 3) * PSM + (c & 7) * 8]
                        : &sBT[((c - 384) >> 3) * PSM + ((c - 384) & 7) * 8];
                    *(int4*)dst = creg[k];
                }
            }
            __syncthreads();
        }
    }
}

// ==========================================================================
// TIER 1 (R11-verified): prep4 + main8 — used if ws fits params only.
// ==========================================================================
__global__ __launch_bounds__(256) void gif_prep4(
        const float* __restrict__ W, const float* __restrict__ alpha,
        const float* __restrict__ h,
        unsigned short* __restrict__ whp, unsigned short* __restrict__ alp) {
    const int x = blockIdx.x;
    const int t = threadIdx.x;
    if (x < NN) {
        const int n = x;
        for (int idx = t; idx < 64 * 64; idx += 256) {
            int d = idx & 63;
            whp[n * WHP_N + idx] = f2bf(W[n * ED * ED + idx] * h[n * ED + d]);
        }
        for (int idx = t; idx < 8 * 64; idx += 256)
            alp[n * ALP_N + (40 + (idx >> 6)) * 64 + (idx & 63)] = 0;
        for (int idx = t; idx < 40 * 24; idx += 256) {
            int i = idx / 24, f = 40 + idx - i * 24;
            alp[n * ALP_N + i * 64 + f] = 0;
        }
    } else {
        const int f = x - NN;
        for (int idx = t; idx < NI * NN; idx += 256) {
            int i = idx / NN, n = idx - i * NN;
            alp[n * ALP_N + i * 64 + f] = f2bf(alpha[(f * NI + i) * NN + n]);
        }
    }
}

__global__ __launch_bounds__(256, 2) void gif_main8(
        const float* __restrict__ B0, const float* __restrict__ Bi,
        const unsigned short* __restrict__ whp,
        const unsigned short* __restrict__ alp,
        float* __restrict__ out) {
    const int bg = blockIdx.x;
    const int ng = blockIdx.y;
    const int t = threadIdx.x;
    const int lane = t & 63, w = t >> 6;
    const int quad = lane >> 4, l15 = lane & 15, fo = quad * 8;
    const int n = ng * 4 + w;

    __shared__ __align__(16) unsigned short sBi[48 * PSM];
    __shared__ __align__(16) unsigned short sBT[64 * PSM];

    float4 rbi[3], rb0[3];
    {
        const float4* biv = (const float4*)(Bi + (size_t)(bg * 4) * NI * ED);
        const float4* b0v = (const float4*)(B0 + (size_t)(bg * 4) * NF * ED);
#pragma unroll
        for (int k = 0; k < 3; ++k) {
            const int c = t + k * 256;
            if (c < 640) { rbi[k] = biv[c]; rb0[k] = b0v[c]; }
        }
    }

    bf16x8 alA[3][2], whB[4][2];
    {
        const unsigned short* ap = alp + n * ALP_N;
        const unsigned short* wp = whp + n * WHP_N;
#pragma unroll
        for (int m = 0; m < 3; ++m)
#pragma unroll
            for (int s = 0; s < 2; ++s)
                alA[m][s] = ld_frag(&ap[(m * 16 + l15) * 64 + s * 32 + fo]);
#pragma unroll
        for (int tt = 0; tt < 4; ++tt)
#pragma unroll
            for (int s = 0; s < 2; ++s)
                whB[tt][s] = ld_frag(&wp[(tt * 16 + l15) * 64 + s * 32 + fo]);
    }

    for (int idx = t; idx < 8 * 64; idx += 256)
        sBi[(40 + (idx >> 6)) * PSM + (idx & 63)] = 0;
    for (int idx = t; idx < 64 * 24; idx += 256) {
        int D = idx / 24, f = 40 + idx - D * 24;
        sBT[D * PSM + f] = 0;
    }

#pragma unroll
    for (int k = 0; k < 3; ++k) {
        const int c = t + k * 256;
        if (c < 640) {
            const int r = c >> 4, col = (c & 15) * 4;
            ushort4 pk;
            pk.x = f2bf(rbi[k].x); pk.y = f2bf(rbi[k].y);
            pk.z = f2bf(rbi[k].z); pk.w = f2bf(rbi[k].w);
            *(ushort4*)&sBi[r * PSM + col] = pk;
            sBT[(col + 0) * PSM + r] = f2bf(rb0[k].x);
            sBT[(col + 1) * PSM + r] = f2bf(rb0[k].y);
            sBT[(col + 2) * PSM + r] = f2bf(rb0[k].z);
            sBT[(col + 3) * PSM + r] = f2bf(rb0[k].w);
        }
    }
    __syncthreads();

#pragma unroll
    for (int j = 0; j < 4; ++j) {
        const int b = bg * 4 + j;

        if (j < 3) {
            const float4* biv = (const float4*)(Bi + (size_t)(b + 1) * NI * ED);
            const float4* b0v = (const float4*)(B0 + (size_t)(b + 1) * NF * ED);
#pragma unroll
            for (int k = 0; k < 3; ++k) {
                const int c = t + k * 256;
                if (c < 640) { rbi[k] = biv[c]; rb0[k] = b0v[c]; }
            }
        }

        bf16x8 biA[3][2];
#pragma unroll
        for (int m = 0; m < 3; ++m)
#pragma unroll
            for (int s = 0; s < 2; ++s)
                biA[m][s] = ld_frag(&sBi[(m * 16 + l15) * PSM + s * 32 + fo]);

        float p[4];
#pragma unroll
        for (int tt = 0; tt < 4; ++tt) {
            bf16x8 bb0 = ld_frag(&sBT[(tt * 16 + l15) * PSM + fo]);
            bf16x8 bb1 = ld_frag(&sBT[(tt * 16 + l15) * PSM + 32 + fo]);
            float acc = 0.f;
#pragma unroll
            for (int m = 0; m < 3; ++m) {
                f32x4 z = {0.f, 0.f, 0.f, 0.f};
                f32x4 T = mfma16(biA[m][0], whB[tt][0], z);
                T = mfma16(biA[m][1], whB[tt][1], T);
                f32x4 G = mfma16(alA[m][0], bb0, z);
                G = mfma16(alA[m][1], bb1, G);
                acc += T[0] * G[0] + T[1] * G[1] + T[2] * G[2] + T[3] * G[3];
            }
            p[tt] = acc;
        }
#pragma unroll
        for (int tt = 0; tt < 4; ++tt) {
            p[tt] += __shfl_xor(p[tt], 16, 64);
            p[tt] += __shfl_xor(p[tt], 32, 64);
        }
        float v = (quad == 0) ? p[0] : (quad == 1) ? p[1] : (quad == 2) ? p[2] : p[3];
        out[((size_t)b * NN + n) * ED + lane] = v;

        if (j < 3) {
            __syncthreads();
#pragma unroll
            for (int k = 0; k < 3; ++k) {
                const int c = t + k * 256;
                if (c < 640) {
                    const int r = c >> 4, col = (c & 15) * 4;
                    ushort4 pk;
                    pk.x = f2bf(rbi[k].x); pk.y = f2bf(rbi[k].y);
                    pk.z = f2bf(rbi[k].z); pk.w = f2bf(rbi[k].w);
                    *(ushort4*)&sBi[r * PSM + col] = pk;
                    sBT[(col + 0) * PSM + r] = f2bf(rb0[k].x);
                    sBT[(col + 1) * PSM + r] = f2bf(rb0[k].y);
                    sBT[(col + 2) * PSM + r] = f2bf(rb0[k].z);
                    sBT[(col + 3) * PSM + r] = f2bf(rb0[k].w);
                }
            }
            __syncthreads();
        }
    }
}

// ==========================================================================
// TIER 0 (R2-verified): no-ws fallback.
// ==========================================================================
#define PS 72
#define WH_N (ED * PS)
#define AL_N (48 * PS)

__device__ __forceinline__ bf16x8 mk_al_frag(const float* __restrict__ alpha,
        int n, int m, int s, int l15, int quad) {
    bf16x8 r;
    const int row = m * 16 + l15;
    const int f0 = s * 32 + quad * 8;
#pragma unroll
    for (int j = 0; j < 8; ++j) {
        const int f = f0 + j;
        float v = (row < NI && f < NF) ? alpha[(f * NI + row) * NN + n] : 0.f;
        r[j] = (__bf16)v;
    }
    return r;
}
__device__ __forceinline__ bf16x8 mk_wh_frag(const float* __restrict__ W,
        const float* __restrict__ h, int n, int tt, int s, int l15, int quad) {
    bf16x8 r;
    const int row = tt * 16 + l15;
    const int k0 = s * 32 + quad * 8;
#pragma unroll
    for (int j = 0; j < 8; ++j) {
        float v = W[n * ED * ED + row * ED + k0 + j] * h[n * ED + k0 + j];
        r[j] = (__bf16)v;
    }
    return r;
}

__global__ __launch_bounds__(256) void gif_mfma(
        const float* __restrict__ B0, const float* __restrict__ Bi,
        const float* __restrict__ W, const float* __restrict__ alpha,
        const float* __restrict__ h, float* __restrict__ out) {
    const int q = blockIdx.x >> 8;
    const int b = blockIdx.x & 255;

    __shared__ __align__(16) unsigned short sBi[48 * PS];
    __shared__ __align__(16) unsigned short sBT[ED * PS];

    const int t = threadIdx.x;
    for (int idx = t; idx < 48 * PS; idx += 256) {
        int i = idx / PS, c = idx - i * PS;
        sBi[idx] = (i < NI && c < ED) ? f2bf(Bi[b * NI * ED + i * ED + c])
                                      : (unsigned short)0;
    }
    for (int idx = t; idx < ED * PS; idx += 256) {
        int D = idx / PS, c = idx - D * PS;
        sBT[idx] = (c < NF) ? f2bf(B0[b * NF * ED + c * ED + D])
                            : (unsigned short)0;
    }
    __syncthreads();

    const int lane = t & 63, w = t >> 6;
    const int quad = lane >> 4, l15 = lane & 15;
    const int fragoff = quad * 8;

    bf16x8 biA[3][2], b0B[4][2];
#pragma unroll
    for (int m = 0; m < 3; ++m)
#pragma unroll
        for (int s = 0; s < 2; ++s)
            biA[m][s] = ld_frag(&sBi[(m * 16 + l15) * PS + s * 32 + fragoff]);
#pragma unroll
    for (int tt = 0; tt < 4; ++tt)
#pragma unroll
        for (int s = 0; s < 2; ++s)
            b0B[tt][s] = ld_frag(&sBT[(tt * 16 + l15) * PS + s * 32 + fragoff]);

#pragma unroll
    for (int rep = 0; rep < 2; ++rep) {
        const int n = q * 8 + w + rep * 4;

        bf16x8 alA[3][2];
#pragma unroll
        for (int m = 0; m < 3; ++m)
#pragma unroll
            for (int s = 0; s < 2; ++s)
                alA[m][s] = mk_al_frag(alpha, n, m, s, l15, quad);

        float p[4];
#pragma unroll
        for (int tt = 0; tt < 4; ++tt) {
            bf16x8 whB2[2];
            whB2[0] = mk_wh_frag(W, h, n, tt, 0, l15, quad);
            whB2[1] = mk_wh_frag(W, h, n, tt, 1, l15, quad);
            float acc = 0.f;
#pragma unroll
            for (int m = 0; m < 3; ++m) {
                f32x4 z = {0.f, 0.f, 0.f, 0.f};
                f32x4 T = mfma16(biA[m][0], whB2[0], z);
                T = mfma16(biA[m][1], whB2[1], T);
                f32x4 G = mfma16(alA[m][0], b0B[tt][0], z);
                G = mfma16(alA[m][1], b0B[tt][1], G);
                acc += T[0] * G[0] + T[1] * G[1] + T[2] * G[2] + T[3] * G[3];
            }
            p[tt] = acc;
        }
#pragma unroll
        for (int tt = 0; tt < 4; ++tt) {
            p[tt] += __shfl_xor(p[tt], 16, 64);
            p[tt] += __shfl_xor(p[tt], 32, 64);
        }
        float v = (quad == 0) ? p[0] : (quad == 1) ? p[1] : (quad == 2) ? p[2] : p[3];
        out[(b * NN + n) * ED + lane] = v;
    }
}

// ==========================================================================
extern "C" void kernel_launch(void* const* d_in, const int* in_sizes, int n_in,
                              void* d_out, int out_size, void* d_ws, size_t ws_size,
                              hipStream_t stream) {
    const float* B0    = (const float*)d_in[0];  // (256,40,64)
    const float* Bi    = (const float*)d_in[1];  // (256,40,64)
    const float* W     = (const float*)d_in[2];  // (40,64,64)
    const float* alpha = (const float*)d_in[3];  // (40,40,40)
    const float* h     = (const float*)d_in[4];  // (40,64,1)
    float* out = (float*)d_out;                  // (256,40,64)

    const size_t need2 =
        (size_t)(NB * BIP_N + NB * B0T_N + NN * WHP_N + NN * ALP_N) * sizeof(unsigned short);
    if (ws_size >= need2) {
        unsigned short* BiP = (unsigned short*)d_ws;
        unsigned short* B0T = BiP + (size_t)NB * BIP_N;
        unsigned short* whp = B0T + (size_t)NB * B0T_N;
        unsigned short* alp = whp + (size_t)NN * WHP_N;
        gif_prep6<<<NB + NN + NF, 256, 0, stream>>>(B0, Bi, W, alpha, h, BiP, B0T, whp, alp);
        gif_main9<<<dim3(64, 10), 256, 0, stream>>>(BiP, B0T, whp, alp, out);
        return;
    }

    const size_t need1 = (size_t)(NN * WHP_N + NN * ALP_N) * sizeof(unsigned short);
    if (ws_size >= need1) {
        unsigned short* whp = (unsigned short*)d_ws;
        unsigned short* alp = whp + (size_t)NN * WHP_N;
        gif_prep4<<<NN + NF, 256, 0, stream>>>(W, alpha, h, whp, alp);
        gif_main8<<<dim3(64, 10), 256, 0, stream>>>(B0, Bi, whp, alp, out);
        return;
    }

    gif_mfma<<<5 * NB, 256, 0, stream>>>(B0, Bi, W, alpha, h, out);
}

// Round 13
// 81.097 us; speedup vs baseline: 1.1572x; 1.1572x over previous
//
#include <hip/hip_runtime.h>
#include <hip/hip_bf16.h>

// Problem constants
#define NF 40   // fields f
#define NI 40   // in_sub i
#define NN 40   // out_sub n
#define ED 64   // embed D, d
#define NB 256  // batch b

typedef __attribute__((ext_vector_type(8))) short   short8;
typedef __attribute__((ext_vector_type(8))) __bf16  bf16x8;
typedef __attribute__((ext_vector_type(4))) float   f32x4;

__device__ __forceinline__ unsigned short f2bf(float x) {
    union { float f; unsigned u; } v; v.f = x;
    unsigned r = v.u + 0x7FFFu + ((v.u >> 16) & 1u);   // RNE
    return (unsigned short)(r >> 16);
}

__device__ __forceinline__ bf16x8 ld_frag(const unsigned short* p) {
    return __builtin_bit_cast(bf16x8, *(const short8*)p);
}

__device__ __forceinline__ f32x4 mfma16(bf16x8 a, bf16x8 b, f32x4 c) {
    return __builtin_amdgcn_mfma_f32_16x16x32_bf16(a, b, c, 0, 0, 0);
}

// ==========================================================================
// FAST PATH: prep4 (params, verified R5/R9/R10/R11) + main8b (R11's main8
// with b-per-block 4 -> 2, grid (128,10) = 5 blocks/CU for latency hiding).
//   whp[n][D(64)][d(64)] = W[n][D][d]*h[n][d]   (bf16, fragment-ready)
//   alp[n][i(48)][f(64)] = alpha[f][i][n]       (pads -> 0)
// ==========================================================================
#define WHP_N (64 * 64)   // 4096
#define ALP_N (48 * 64)   // 3072
#define BPB 2             // b's per block (R11 used 4; 2 doubles block TLP)

// Prep: 80 blocks x 256 thr (byte-identical to verified R5 version).
__global__ __launch_bounds__(256) void gif_prep4(
        const float* __restrict__ W, const float* __restrict__ alpha,
        const float* __restrict__ h,
        unsigned short* __restrict__ whp, unsigned short* __restrict__ alp) {
    const int x = blockIdx.x;
    const int t = threadIdx.x;
    if (x < NN) {
        const int n = x;
        for (int idx = t; idx < 64 * 64; idx += 256) {       // whp coalesced
            int d = idx & 63;
            whp[n * WHP_N + idx] = f2bf(W[n * ED * ED + idx] * h[n * ED + d]);
        }
        for (int idx = t; idx < 8 * 64; idx += 256)          // rows i 40..47
            alp[n * ALP_N + (40 + (idx >> 6)) * 64 + (idx & 63)] = 0;
        for (int idx = t; idx < 40 * 24; idx += 256) {       // cols f 40..63
            int i = idx / 24, f = 40 + idx - i * 24;
            alp[n * ALP_N + i * 64 + f] = 0;
        }
    } else {
        const int f = x - NN;
        for (int idx = t; idx < NI * NN; idx += 256) {       // coalesced read
            int i = idx / NN, n = idx - i * NN;
            alp[n * ALP_N + i * 64 + f] = f2bf(alpha[(f * NI + i) * NN + n]);
        }
    }
}

// Main8b: grid (128, 10) x 256 thr (4 waves). Block = (2 b's, 4 n's).
// Identical structure to R11's verified main8: wave w owns n = ng*4+w,
// params in registers for the whole kernel; b-loop software-pipelines the
// hoisted float4 staging; pads zeroed once.
#define PSM 72
__global__ __launch_bounds__(256, 2) void gif_main8b(
        const float* __restrict__ B0, const float* __restrict__ Bi,
        const unsigned short* __restrict__ whp,
        const unsigned short* __restrict__ alp,
        float* __restrict__ out) {
    const int bg = blockIdx.x;         // 0..127 : b in [bg*BPB, bg*BPB+BPB)
    const int ng = blockIdx.y;         // 0..9   : n in [ng*4, ng*4+4)
    const int t = threadIdx.x;
    const int lane = t & 63, w = t >> 6;
    const int quad = lane >> 4, l15 = lane & 15, fo = quad * 8;
    const int n = ng * 4 + w;

    __shared__ __align__(16) unsigned short sBi[48 * PSM];  // [i][d]  6912 B
    __shared__ __align__(16) unsigned short sBT[64 * PSM];  // [D][f]  9216 B

    // ---- 1. staging loads for first b issued FIRST (coalesced float4) ----
    float4 rbi[3], rb0[3];
    {
        const float4* biv = (const float4*)(Bi + (size_t)(bg * BPB) * NI * ED);
        const float4* b0v = (const float4*)(B0 + (size_t)(bg * BPB) * NF * ED);
#pragma unroll
        for (int k = 0; k < 3; ++k) {
            const int c = t + k * 256;
            if (c < 640) { rbi[k] = biv[c]; rb0[k] = b0v[c]; }
        }
    }

    // ---- 2. this wave's n-params: 14 b128 gathers, ONCE (overlap above) ----
    bf16x8 alA[3][2], whB[4][2];
    {
        const unsigned short* ap = alp + n * ALP_N;
        const unsigned short* wp = whp + n * WHP_N;
#pragma unroll
        for (int m = 0; m < 3; ++m)
#pragma unroll
            for (int s = 0; s < 2; ++s)
                alA[m][s] = ld_frag(&ap[(m * 16 + l15) * 64 + s * 32 + fo]);
#pragma unroll
        for (int tt = 0; tt < 4; ++tt)
#pragma unroll
            for (int s = 0; s < 2; ++s)
                whB[tt][s] = ld_frag(&wp[(tt * 16 + l15) * 64 + s * 32 + fo]);
    }

    // ---- 3. zero pads ONCE ----
    for (int idx = t; idx < 8 * 64; idx += 256)          // sBi rows i 40..47
        sBi[(40 + (idx >> 6)) * PSM + (idx & 63)] = 0;
    for (int idx = t; idx < 64 * 24; idx += 256) {       // sBT cols f 40..63
        int D = idx / 24, f = 40 + idx - D * 24;
        sBT[D * PSM + f] = 0;
    }

    // ---- 4. convert + write first b's staging ----
#pragma unroll
    for (int k = 0; k < 3; ++k) {
        const int c = t + k * 256;
        if (c < 640) {
            const int r = c >> 4, col = (c & 15) * 4;
            ushort4 pk;
            pk.x = f2bf(rbi[k].x); pk.y = f2bf(rbi[k].y);
            pk.z = f2bf(rbi[k].z); pk.w = f2bf(rbi[k].w);
            *(ushort4*)&sBi[r * PSM + col] = pk;
            sBT[(col + 0) * PSM + r] = f2bf(rb0[k].x);
            sBT[(col + 1) * PSM + r] = f2bf(rb0[k].y);
            sBT[(col + 2) * PSM + r] = f2bf(rb0[k].z);
            sBT[(col + 3) * PSM + r] = f2bf(rb0[k].w);
        }
    }
    __syncthreads();

    // ---- 5. b-loop ----
#pragma unroll
    for (int j = 0; j < BPB; ++j) {
        const int b = bg * BPB + j;

        if (j < BPB - 1) {   // prefetch next b's staging into registers
            const float4* biv = (const float4*)(Bi + (size_t)(b + 1) * NI * ED);
            const float4* b0v = (const float4*)(B0 + (size_t)(b + 1) * NF * ED);
#pragma unroll
            for (int k = 0; k < 3; ++k) {
                const int c = t + k * 256;
                if (c < 640) { rbi[k] = biv[c]; rb0[k] = b0v[c]; }
            }
        }

        // per-b fragments from LDS + 48-MFMA body
        bf16x8 biA[3][2];
#pragma unroll
        for (int m = 0; m < 3; ++m)
#pragma unroll
            for (int s = 0; s < 2; ++s)
                biA[m][s] = ld_frag(&sBi[(m * 16 + l15) * PSM + s * 32 + fo]);

        float p[4];
#pragma unroll
        for (int tt = 0; tt < 4; ++tt) {
            bf16x8 bb0 = ld_frag(&sBT[(tt * 16 + l15) * PSM + fo]);
            bf16x8 bb1 = ld_frag(&sBT[(tt * 16 + l15) * PSM + 32 + fo]);
            float acc = 0.f;
#pragma unroll
            for (int m = 0; m < 3; ++m) {
                f32x4 z = {0.f, 0.f, 0.f, 0.f};
                f32x4 T = mfma16(biA[m][0], whB[tt][0], z);
                T = mfma16(biA[m][1], whB[tt][1], T);
                f32x4 G = mfma16(alA[m][0], bb0, z);
                G = mfma16(alA[m][1], bb1, G);
                acc += T[0] * G[0] + T[1] * G[1] + T[2] * G[2] + T[3] * G[3];
            }
            p[tt] = acc;
        }
#pragma unroll
        for (int tt = 0; tt < 4; ++tt) {
            p[tt] += __shfl_xor(p[tt], 16, 64);
            p[tt] += __shfl_xor(p[tt], 32, 64);
        }
        float v = (quad == 0) ? p[0] : (quad == 1) ? p[1] : (quad == 2) ? p[2] : p[3];
        out[((size_t)b * NN + n) * ED + lane] = v;

        if (j < BPB - 1) {   // restage for b+1 between two barriers
            __syncthreads();
#pragma unroll
            for (int k = 0; k < 3; ++k) {
                const int c = t + k * 256;
                if (c < 640) {
                    const int r = c >> 4, col = (c & 15) * 4;
                    ushort4 pk;
                    pk.x = f2bf(rbi[k].x); pk.y = f2bf(rbi[k].y);
                    pk.z = f2bf(rbi[k].z); pk.w = f2bf(rbi[k].w);
                    *(ushort4*)&sBi[r * PSM + col] = pk;
                    sBT[(col + 0) * PSM + r] = f2bf(rb0[k].x);
                    sBT[(col + 1) * PSM + r] = f2bf(rb0[k].y);
                    sBT[(col + 2) * PSM + r] = f2bf(rb0[k].z);
                    sBT[(col + 3) * PSM + r] = f2bf(rb0[k].w);
                }
            }
            __syncthreads();
        }
    }
}

// ==========================================================================
// TIER 0 (R2-verified): no-ws fallback.
// ==========================================================================
#define PS 72

__device__ __forceinline__ bf16x8 mk_al_frag(const float* __restrict__ alpha,
        int n, int m, int s, int l15, int quad) {
    bf16x8 r;
    const int row = m * 16 + l15;
    const int f0 = s * 32 + quad * 8;
#pragma unroll
    for (int j = 0; j < 8; ++j) {
        const int f = f0 + j;
        float v = (row < NI && f < NF) ? alpha[(f * NI + row) * NN + n] : 0.f;
        r[j] = (__bf16)v;
    }
    return r;
}
__device__ __forceinline__ bf16x8 mk_wh_frag(const float* __restrict__ W,
        const float* __restrict__ h, int n, int tt, int s, int l15, int quad) {
    bf16x8 r;
    const int row = tt * 16 + l15;
    const int k0 = s * 32 + quad * 8;
#pragma unroll
    for (int j = 0; j < 8; ++j) {
        float v = W[n * ED * ED + row * ED + k0 + j] * h[n * ED + k0 + j];
        r[j] = (__bf16)v;
    }
    return r;
}

__global__ __launch_bounds__(256) void gif_mfma(
        const float* __restrict__ B0, const float* __restrict__ Bi,
        const float* __restrict__ W, const float* __restrict__ alpha,
        const float* __restrict__ h, float* __restrict__ out) {
    const int q = blockIdx.x >> 8;
    const int b = blockIdx.x & 255;

    __shared__ __align__(16) unsigned short sBi[48 * PS];
    __shared__ __align__(16) unsigned short sBT[ED * PS];

    const int t = threadIdx.x;
    for (int idx = t; idx < 48 * PS; idx += 256) {
        int i = idx / PS, c = idx - i * PS;
        sBi[idx] = (i < NI && c < ED) ? f2bf(Bi[b * NI * ED + i * ED + c])
                                      : (unsigned short)0;
    }
    for (int idx = t; idx < ED * PS; idx += 256) {
        int D = idx / PS, c = idx - D * PS;
        sBT[idx] = (c < NF) ? f2bf(B0[b * NF * ED + c * ED + D])
                            : (unsigned short)0;
    }
    __syncthreads();

    const int lane = t & 63, w = t >> 6;
    const int quad = lane >> 4, l15 = lane & 15;
    const int fragoff = quad * 8;

    bf16x8 biA[3][2], b0B[4][2];
#pragma unroll
    for (int m = 0; m < 3; ++m)
#pragma unroll
        for (int s = 0; s < 2; ++s)
            biA[m][s] = ld_frag(&sBi[(m * 16 + l15) * PS + s * 32 + fragoff]);
#pragma unroll
    for (int tt = 0; tt < 4; ++tt)
#pragma unroll
        for (int s = 0; s < 2; ++s)
            b0B[tt][s] = ld_frag(&sBT[(tt * 16 + l15) * PS + s * 32 + fragoff]);

#pragma unroll
    for (int rep = 0; rep < 2; ++rep) {
        const int n = q * 8 + w + rep * 4;

        bf16x8 alA[3][2];
#pragma unroll
        for (int m = 0; m < 3; ++m)
#pragma unroll
            for (int s = 0; s < 2; ++s)
                alA[m][s] = mk_al_frag(alpha, n, m, s, l15, quad);

        float p[4];
#pragma unroll
        for (int tt = 0; tt < 4; ++tt) {
            bf16x8 whB2[2];
            whB2[0] = mk_wh_frag(W, h, n, tt, 0, l15, quad);
            whB2[1] = mk_wh_frag(W, h, n, tt, 1, l15, quad);
            float acc = 0.f;
#pragma unroll
            for (int m = 0; m < 3; ++m) {
                f32x4 z = {0.f, 0.f, 0.f, 0.f};
                f32x4 T = mfma16(biA[m][0], whB2[0], z);
                T = mfma16(biA[m][1], whB2[1], T);
                f32x4 G = mfma16(alA[m][0], b0B[tt][0], z);
                G = mfma16(alA[m][1], b0B[tt][1], G);
                acc += T[0] * G[0] + T[1] * G[1] + T[2] * G[2] + T[3] * G[3];
            }
            p[tt] = acc;
        }
#pragma unroll
        for (int tt = 0; tt < 4; ++tt) {
            p[tt] += __shfl_xor(p[tt], 16, 64);
            p[tt] += __shfl_xor(p[tt], 32, 64);
        }
        float v = (quad == 0) ? p[0] : (quad == 1) ? p[1] : (quad == 2) ? p[2] : p[3];
        out[(b * NN + n) * ED + lane] = v;
    }
}

// ==========================================================================
extern "C" void kernel_launch(void* const* d_in, const int* in_sizes, int n_in,
                              void* d_out, int out_size, void* d_ws, size_t ws_size,
                              hipStream_t stream) {
    const float* B0    = (const float*)d_in[0];  // (256,40,64)
    const float* Bi    = (const float*)d_in[1];  // (256,40,64)
    const float* W     = (const float*)d_in[2];  // (40,64,64)
    const float* alpha = (const float*)d_in[3];  // (40,40,40)
    const float* h     = (const float*)d_in[4];  // (40,64,1)
    float* out = (float*)d_out;                  // (256,40,64)

    const size_t need1 = (size_t)(NN * WHP_N + NN * ALP_N) * sizeof(unsigned short);
    if (ws_size >= need1) {
        unsigned short* whp = (unsigned short*)d_ws;
        unsigned short* alp = whp + (size_t)NN * WHP_N;
        gif_prep4<<<NN + NF, 256, 0, stream>>>(W, alpha, h, whp, alp);
        gif_main8b<<<dim3(NB / BPB, 10), 256, 0, stream>>>(B0, Bi, whp, alp, out);
        return;
    }

    gif_mfma<<<5 * NB, 256, 0, stream>>>(B0, Bi, W, alpha, h, out);
}